// Round 2
// baseline (1470.171 us; speedup 1.0000x reference)
//
#include <hip/hip_runtime.h>

#define NB 16
#define NC 256
#define NH 64
#define NW 64
#define NK 1024
#define HW (NH * NW)          // 4096
#define NPOS (NB * HW)        // 65536
#define NOUT (NB * NC * HW)   // 16777216

__device__ __forceinline__ float sq_rn(float x) { return __fmul_rn(x, x); }

// Exact replica of numpy pairwise_sum for sum(a*a) over n=256 elements with
// given element stride: n=256 > PW_BLOCKSIZE(128) -> split 128+128; each
// 128-half uses 8 accumulators r[0..7] (r[j] init from first block, then
// += per 8-chunk), combined ((r0+r1)+(r2+r3))+((r4+r5)+(r6+r7)); halves
// joined by one add. Squares rounded before summing (no FMA) — matches
// numpy's zf*zf temp followed by np.sum.
__device__ __forceinline__ float pairwise_sumsq_256(const float* __restrict__ a,
                                                    int stride) {
    float s_half[2];
#pragma unroll
    for (int h = 0; h < 2; ++h) {
        const float* base = a + (size_t)(h * 128) * stride;
        float r[8];
#pragma unroll
        for (int j = 0; j < 8; ++j) r[j] = sq_rn(base[(size_t)j * stride]);
        for (int i = 8; i < 128; i += 8) {
#pragma unroll
            for (int j = 0; j < 8; ++j)
                r[j] = __fadd_rn(r[j], sq_rn(base[(size_t)(i + j) * stride]));
        }
        s_half[h] = __fadd_rn(
            __fadd_rn(__fadd_rn(r[0], r[1]), __fadd_rn(r[2], r[3])),
            __fadd_rn(__fadd_rn(r[4], r[5]), __fadd_rn(r[6], r[7])));
    }
    return __fadd_rn(s_half[0], s_half[1]);
}

// ---------------------------------------------------------------------------
// Kernel A: cnorm[k] = numpy-fp32 sum(codebook[k]^2)
// ---------------------------------------------------------------------------
__global__ __launch_bounds__(256) void cnorm_kernel(const float* __restrict__ cb,
                                                    float* __restrict__ cnorm) {
    int k = blockIdx.x * 256 + threadIdx.x;
    if (k < NK) {
        cnorm[k] = pairwise_sumsq_256(cb + (size_t)k * NC, 1);
    }
}

// ---------------------------------------------------------------------------
// Kernel B: per position p, argmin_k fl32( fl32(znorm_p + cnorm_k) - 2*dot )
// with dot = single sequential fp32-FMA chain over ascending c (matches BLAS
// sgemm micro-kernel accumulation). First-occurrence tie-break (lowest k).
// Grid: 1024 blocks = 16 batches x 64 h-rows. Block: 256 threads = 4 waves.
// Each wave handles all 64 w positions (p = lane) for a 256-code quarter.
// ---------------------------------------------------------------------------
__global__ __launch_bounds__(256) void argmin_kernel(const float* __restrict__ z,
                                                     const float* __restrict__ cb,
                                                     const float* __restrict__ cnorm,
                                                     int* __restrict__ idx_ws,
                                                     float* __restrict__ idx_out) {
    const int tile = blockIdx.x;      // 0..1023
    const int b = tile >> 6;          // 0..15
    const int h = tile & 63;          // 0..63
    const int lane = threadIdx.x & 63;
    const int wave = threadIdx.x >> 6;  // 0..3

    // z[((b*NC + c)*NH + h)*NW + w]; thread owns w = lane
    const float* zbase = z + (size_t)b * NC * HW + h * NW + lane;

    // numpy-exact ||z_p||^2 (pairwise order, stride HW across channels)
    const float znorm = pairwise_sumsq_256(zbase, HW);

    // wave-uniform base of this wave's 256-code quarter
    const int kbase0 = __builtin_amdgcn_readfirstlane(wave * 256);

    float best = 3.4e38f;
    int bidx = 0;

    for (int pass = 0; pass < 16; ++pass) {
        const int k0 = kbase0 + pass * 16;
        float acc[16];
#pragma unroll
        for (int i = 0; i < 16; ++i) acc[i] = 0.f;

        for (int c0 = 0; c0 < NC; c0 += 8) {
            float vz[8];
#pragma unroll
            for (int j = 0; j < 8; ++j) vz[j] = zbase[(size_t)(c0 + j) * HW];
#pragma unroll
            for (int kk = 0; kk < 16; ++kk) {
                const float* cbp = cb + (size_t)(k0 + kk) * NC + c0;
#pragma unroll
                for (int j = 0; j < 8; ++j)
                    acc[kk] = __fmaf_rn(vz[j], cbp[j], acc[kk]);
            }
        }

#pragma unroll
        for (int kk = 0; kk < 16; ++kk) {
            const int k = k0 + kk;
            // d = fl( fl(znorm + cnorm_k) - 2*dot_k )  -- reference fp32 order
            const float sc = __fsub_rn(__fadd_rn(znorm, cnorm[k]),
                                       __fmul_rn(2.0f, acc[kk]));
            // strict < with ascending k == np.argmin first-occurrence
            if (sc < best || (sc == best && k < bidx)) {
                best = sc;
                bidx = k;
            }
        }
    }

    __shared__ float sval[4][64];
    __shared__ int sidx[4][64];
    sval[wave][lane] = best;
    sidx[wave][lane] = bidx;
    __syncthreads();

    if (threadIdx.x < 64) {
        float bv = sval[0][lane];
        int bi = sidx[0][lane];
#pragma unroll
        for (int w = 1; w < 4; ++w) {
            float v = sval[w][lane];
            int i2 = sidx[w][lane];
            if (v < bv || (v == bv && i2 < bi)) {
                bv = v;
                bi = i2;
            }
        }
        const int pos = b * HW + h * NW + lane;
        idx_ws[pos] = bi;
        idx_out[pos] = (float)bi;   // indices output stored as float32
    }
}

// ---------------------------------------------------------------------------
// Kernel C: out[b,c,h,w] = cb[idx[b,h,w]][c]; accumulate sum((zq - z)^2)
// ---------------------------------------------------------------------------
__global__ __launch_bounds__(256) void gather_loss_kernel(const float* __restrict__ z,
                                                          const float* __restrict__ cb,
                                                          const int* __restrict__ idx_ws,
                                                          float* __restrict__ out,
                                                          double* __restrict__ loss_acc) {
    const unsigned g = blockIdx.x * 256u + threadIdx.x;  // float4 index
    const unsigned e = g * 4u;                           // element index
    const unsigned w = e & 63u;
    const unsigned h = (e >> 6) & 63u;
    const unsigned c = (e >> 12) & 255u;
    const unsigned b = e >> 20;

    const unsigned p = b * HW + h * NW + w;  // divisible by 4

    const int4 iv = *(const int4*)(idx_ws + p);
    const float4 z4 = *(const float4*)(z + e);

    float4 o;
    o.x = cb[(size_t)iv.x * NC + c];
    o.y = cb[(size_t)iv.y * NC + c];
    o.z = cb[(size_t)iv.z * NC + c];
    o.w = cb[(size_t)iv.w * NC + c];

    *(float4*)(out + e) = o;

    const float d0 = o.x - z4.x;
    const float d1 = o.y - z4.y;
    const float d2 = o.z - z4.z;
    const float d3 = o.w - z4.w;
    float part = d0 * d0 + d1 * d1 + d2 * d2 + d3 * d3;

#pragma unroll
    for (int off = 32; off > 0; off >>= 1) part += __shfl_down(part, off, 64);

    __shared__ float wsum[4];
    const int lane = threadIdx.x & 63;
    const int wave = threadIdx.x >> 6;
    if (lane == 0) wsum[wave] = part;
    __syncthreads();
    if (threadIdx.x == 0) {
        float s = wsum[0] + wsum[1] + wsum[2] + wsum[3];
        atomicAdd(loss_acc, (double)s);
    }
}

// ---------------------------------------------------------------------------
// Kernel D: loss = (1 + beta) * sum / NOUT
// ---------------------------------------------------------------------------
__global__ void finalize_kernel(const double* __restrict__ loss_acc,
                                float* __restrict__ out_loss) {
    if (threadIdx.x == 0) {
        *out_loss = (float)(1.25 * (*loss_acc) / (double)NOUT);
    }
}

extern "C" void kernel_launch(void* const* d_in, const int* in_sizes, int n_in,
                              void* d_out, int out_size, void* d_ws, size_t ws_size,
                              hipStream_t stream) {
    const float* z = (const float*)d_in[0];
    const float* cb = (const float*)d_in[1];

    float* out = (float*)d_out;            // [16,256,64,64]
    float* loss_out = out + NOUT;          // scalar
    float* idx_out = out + NOUT + 1;       // [16,1,64,64] as float

    double* loss_acc = (double*)d_ws;                      // 8 B (zeroed below)
    float* cnorm = (float*)((char*)d_ws + 64);             // 4 KB
    int* idx_ws = (int*)((char*)d_ws + 64 + NK * 4);       // 256 KB

    hipMemsetAsync(d_ws, 0, 64, stream);
    cnorm_kernel<<<(NK + 255) / 256, 256, 0, stream>>>(cb, cnorm);
    argmin_kernel<<<NB * NH, 256, 0, stream>>>(z, cb, cnorm, idx_ws, idx_out);
    gather_loss_kernel<<<NOUT / 1024, 256, 0, stream>>>(z, cb, idx_ws, out, loss_acc);
    finalize_kernel<<<1, 64, 0, stream>>>(loss_acc, loss_out);
}